// Round 13
// baseline (2254.862 us; speedup 1.0000x reference)
//
#include <hip/hip_runtime.h>
#include <stdint.h>

#define B_ 64
#define T_ 2048
#define H_ 128
#define G_ 512
#define NL 3
#define OUT_ 10
#define CHK 16
#define NCH (T_/CHK)

typedef __attribute__((ext_vector_type(8))) short bf16x8;
typedef __attribute__((ext_vector_type(4))) float f32x4;

#define MF(A,BW,C) __builtin_amdgcn_mfma_f32_16x16x32_bf16(A,BW,C,0,0,0)

__device__ __forceinline__ uint16_t f2bf(float f){
  union { float f; uint32_t u; } v; v.f = f;
  uint32_t u = v.u;
  uint32_t r = (u + 0x7FFFu + ((u >> 16) & 1u)) >> 16;
  return (uint16_t)r;
}

// Barrier WITHOUT vmcnt(0) drain: LDS ordering only.
__device__ __forceinline__ void wg_barrier(){
  asm volatile("s_waitcnt lgkmcnt(0)" ::: "memory");
  __builtin_amdgcn_sched_barrier(0);
  __builtin_amdgcn_s_barrier();
  __builtin_amdgcn_sched_barrier(0);
}

// ---------------------------------------------------------------- prep
// Weights pre-scaled per gate (i,f,o: -log2e; g: +2*log2e) so gates become
// rcp(1+exp2(x)); bias likewise pre-scaled (folded into MFMA C-init).
__global__ void prep_kernel(const float* __restrict__ x,
                            const float* __restrict__ wih, const float* __restrict__ whh,
                            const float* __restrict__ bih, const float* __restrict__ bhh,
                            uint16_t* __restrict__ A0, uint16_t* __restrict__ WIHS,
                            uint16_t* __restrict__ WHHS, float* __restrict__ BSCL,
                            int* __restrict__ flags){
  int stride = gridDim.x * blockDim.x;
  int g0 = blockIdx.x * blockDim.x + threadIdx.x;
  for (int i = g0; i < B_*T_*H_; i += stride) A0[i] = f2bf(x[i]);
  for (int i = g0; i < NL*G_*H_; i += stride){
    int n = (i >> 7) & 511;
    float sc = ((n >> 7) == 2) ? 2.88539008f : -1.44269504f;
    WIHS[i] = f2bf(wih[i] * sc);
    WHHS[i] = f2bf(whh[i] * sc);
  }
  for (int i = g0; i < NL*G_; i += stride){
    float sc = (((i & 511) >> 7) == 2) ? 2.88539008f : -1.44269504f;
    BSCL[i] = (bih[i] + bhh[i]) * sc;
  }
  if (g0 < 32) flags[g0] = 0;
}

// ---------------------------------------------------------------- fused pipelined scan
// R13: 12 WGs — layer = wg/4, q = wg%4, WG owns 16 REAL batches (b0=q*16).
// MFMA A-tile rows = the 16 batches (no duplicate-row waste: 100% dense).
// Per step per wave: K=256 fused chain (C=bias, 4 x-MFMAs, 4 h-MFMAs) x
// 4 gate-blocks = 32 MFMAs covering 16 batches x 16 cols x 4 gates.
// Lane (hi,lo) of wave w owns cells (b=hi*4+r, j=w*16+lo), r=0..3 — all 4
// gates lane-local, no selects. h ping-pongs in a 16x128 LDS tile with the
// R4-proj-verified swizzle (row*256 + (off ^ ((row&7)<<4))): reads and
// writes both <=2-way (free). Layer handoff: proven chunk flags, 1:1 WGs.
#define STEPF(tcur, AX) do { \
    bf16x8 af0 = *(const bf16x8*)((const char*)RBp + afo0); \
    bf16x8 af1 = *(const bf16x8*)((const char*)RBp + afo1); \
    bf16x8 af2 = *(const bf16x8*)((const char*)RBp + afo2); \
    bf16x8 af3 = *(const bf16x8*)((const char*)RBp + afo3); \
    f32x4 a0 = MF(AX[0], bwih[0][0], binit0); \
    f32x4 a1 = MF(AX[0], bwih[1][0], binit1); \
    f32x4 a2 = MF(AX[0], bwih[2][0], binit2); \
    f32x4 a3 = MF(AX[0], bwih[3][0], binit3); \
    a0 = MF(AX[1], bwih[0][1], a0); a1 = MF(AX[1], bwih[1][1], a1); \
    a2 = MF(AX[1], bwih[2][1], a2); a3 = MF(AX[1], bwih[3][1], a3); \
    a0 = MF(AX[2], bwih[0][2], a0); a1 = MF(AX[2], bwih[1][2], a1); \
    a2 = MF(AX[2], bwih[2][2], a2); a3 = MF(AX[2], bwih[3][2], a3); \
    a0 = MF(AX[3], bwih[0][3], a0); a1 = MF(AX[3], bwih[1][3], a1); \
    a2 = MF(AX[3], bwih[2][3], a2); a3 = MF(AX[3], bwih[3][3], a3); \
    { int tc_ = (tcur) + 2; tc_ = tc_ > T_-1 ? T_-1 : tc_; \
      const uint16_t* xb_ = Xin + (size_t)tc_ * H_; \
      AX[0] = *(const bf16x8*)(xb_ + xo0); \
      AX[1] = *(const bf16x8*)(xb_ + xo1); \
      AX[2] = *(const bf16x8*)(xb_ + xo2); \
      AX[3] = *(const bf16x8*)(xb_ + xo3); } \
    a0 = MF(af0, bwhh[0][0], a0); a1 = MF(af0, bwhh[1][0], a1); \
    a2 = MF(af0, bwhh[2][0], a2); a3 = MF(af0, bwhh[3][0], a3); \
    a0 = MF(af1, bwhh[0][1], a0); a1 = MF(af1, bwhh[1][1], a1); \
    a2 = MF(af1, bwhh[2][1], a2); a3 = MF(af1, bwhh[3][1], a3); \
    a0 = MF(af2, bwhh[0][2], a0); a1 = MF(af2, bwhh[1][2], a1); \
    a2 = MF(af2, bwhh[2][2], a2); a3 = MF(af2, bwhh[3][2], a3); \
    a0 = MF(af3, bwhh[0][3], a0); a1 = MF(af3, bwhh[1][3], a1); \
    a2 = MF(af3, bwhh[2][3], a2); a3 = MF(af3, bwhh[3][3], a3); \
    _Pragma("unroll") \
    for (int r = 0; r < 4; ++r){ \
      float iv = __builtin_amdgcn_rcpf(1.0f + __builtin_amdgcn_exp2f(a0[r])); \
      float fv = __builtin_amdgcn_rcpf(1.0f + __builtin_amdgcn_exp2f(a1[r])); \
      float gt = __builtin_amdgcn_rcpf(1.0f + __builtin_amdgcn_exp2f(a2[r])); \
      float ov = __builtin_amdgcn_rcpf(1.0f + __builtin_amdgcn_exp2f(a3[r])); \
      float gv = __builtin_fmaf(-2.0f, gt, 1.0f); \
      cs[r] = fv * cs[r] + iv * gv; \
      float tt = __builtin_amdgcn_rcpf(1.0f + __builtin_amdgcn_exp2f(2.88539008f * cs[r])); \
      float th = __builtin_fmaf(-2.0f, tt, 1.0f); \
      float hval = ov * th; \
      uint32_t hp; \
      asm("v_cvt_pk_bf16_f32 %0, %1, %2" : "=v"(hp) : "v"(hval), "v"(hval)); \
      *(uint16_t*)((char*)WBp + hwo[r]) = (uint16_t)hp; \
      if (layer < 2){ \
        Hout[houtB[r] + (size_t)(tcur)*H_] = (uint16_t)hp; \
      } else if ((tcur) == T_-1){ \
        hlast[hlB[r]] = hval; \
      } \
    } \
    wg_barrier(); \
    { uint16_t* tmp_ = RBp; RBp = WBp; WBp = tmp_; } \
  } while(0)

__global__ __launch_bounds__(512, 2) void fused_kernel(
    const uint16_t* __restrict__ A0, uint16_t* __restrict__ H1,
    uint16_t* __restrict__ H2, const uint16_t* __restrict__ WIHS,
    const uint16_t* __restrict__ WHHS, const float* __restrict__ BSCL,
    float* __restrict__ hlast, int* __restrict__ flags){
  __shared__ uint16_t hb0[16*128];
  __shared__ uint16_t hb1[16*128];
  int tid = threadIdx.x;
  int wg = blockIdx.x;
  int layer = wg >> 2, q = wg & 3;
  int b0 = q * 16;
  int w = tid >> 6, l = tid & 63, lo = l & 15, hi = l >> 4;
  int j = w*16 + lo;

  const uint16_t* Xin = (layer == 0) ? A0 : ((layer == 1) ? H1 : H2);
  uint16_t* Hout = (layer == 0) ? H1 : H2;   // unused for layer 2
  int* flgP = flags + layer*4 + q;           // producer flag (layer<2)
  int* flgC = flags + (layer-1)*4 + q;       // consumer flag (layer>0)

  const uint16_t* wihL = WIHS + layer*G_*H_;
  const uint16_t* whhL = WHHS + layer*G_*H_;

  bf16x8 bwih[4][4], bwhh[4][4];
#pragma unroll
  for (int g = 0; g < 4; ++g)
#pragma unroll
    for (int kc = 0; kc < 4; ++kc){
      bwih[g][kc] = *(const bf16x8*)(wihL + (g*128 + j)*H_ + kc*32 + hi*8);
      bwhh[g][kc] = *(const bf16x8*)(whhL + (g*128 + j)*H_ + kc*32 + hi*8);
    }

  float bs0 = BSCL[layer*G_ +       j];
  float bs1 = BSCL[layer*G_ + 128 + j];
  float bs2 = BSCL[layer*G_ + 256 + j];
  float bs3 = BSCL[layer*G_ + 384 + j];
  f32x4 binit0 = {bs0,bs0,bs0,bs0};
  f32x4 binit1 = {bs1,bs1,bs1,bs1};
  f32x4 binit2 = {bs2,bs2,bs2,bs2};
  f32x4 binit3 = {bs3,bs3,bs3,bs3};

  // h-tile A-frag read offsets: row = lo (real batch), 16B chunk kc at
  // byte lo*256 + ((kc*64 + hi*16) ^ ((lo&7)<<4)).  <=2-way conflicts.
  int swr = (lo & 7) << 4;
  int afo0 = lo*256 + ((  0 + hi*16) ^ swr);
  int afo1 = lo*256 + (( 64 + hi*16) ^ swr);
  int afo2 = lo*256 + ((128 + hi*16) ^ swr);
  int afo3 = lo*256 + ((192 + hi*16) ^ swr);
  // h writes: cell (row = hi*4+r, col j): byte row*256 + ((j*2) ^ ((row&7)<<4))
  int hwo[4]; size_t houtB[4]; int hlB[4];
#pragma unroll
  for (int r = 0; r < 4; ++r){
    int row = hi*4 + r;
    hwo[r] = row*256 + ((j*2) ^ ((row & 7) << 4));
    houtB[r] = (size_t)(b0 + row) * T_ * H_ + j;
    hlB[r] = (b0 + row)*H_ + j;
  }

  // x A-frag global offsets: row = batch lo
  int xo0 = (b0 + lo)*T_*H_ +  0*32 + hi*8;
  int xo1 = (b0 + lo)*T_*H_ +  1*32 + hi*8;
  int xo2 = (b0 + lo)*T_*H_ +  2*32 + hi*8;
  int xo3 = (b0 + lo)*T_*H_ +  3*32 + hi*8;

  float cs[4] = {0.f, 0.f, 0.f, 0.f};
  for (int i = tid; i < 16*128; i += 512){ hb0[i] = 0; hb1[i] = 0; }

  if (layer > 0 && tid == 0){
    while (__hip_atomic_load(flgC, __ATOMIC_ACQUIRE, __HIP_MEMORY_SCOPE_AGENT) < 2)
      __builtin_amdgcn_s_sleep(8);
  }
  __syncthreads();

  bf16x8 axA[4], axB[4];
  {
    const uint16_t* xb = Xin;          // t = 0
    axA[0] = *(const bf16x8*)(xb + xo0);
    axA[1] = *(const bf16x8*)(xb + xo1);
    axA[2] = *(const bf16x8*)(xb + xo2);
    axA[3] = *(const bf16x8*)(xb + xo3);
    xb = Xin + H_;                     // t = 1
    axB[0] = *(const bf16x8*)(xb + xo0);
    axB[1] = *(const bf16x8*)(xb + xo1);
    axB[2] = *(const bf16x8*)(xb + xo2);
    axB[3] = *(const bf16x8*)(xb + xo3);
  }

  uint16_t* RBp = hb0;
  uint16_t* WBp = hb1;

  for (int c = 0; c < NCH; ++c){
    int tb = c * CHK;
#pragma unroll
    for (int kk = 0; kk < 4; ++kk){
      int t = tb + kk*4;
      STEPF(t,   axA);   // consumes x[t],   reloads axA with x[t+2]
      STEPF(t+1, axB);   // consumes x[t+1], reloads axB with x[t+3]
      STEPF(t+2, axA);
      STEPF(t+3, axB);
    }
    if (layer < 2){
      asm volatile("s_waitcnt vmcnt(0)" ::: "memory");
      __syncthreads();
      if (tid == 0)
        __hip_atomic_store(flgP, c + 1, __ATOMIC_RELEASE, __HIP_MEMORY_SCOPE_AGENT);
    }
    if (layer > 0 && c + 1 < NCH){
      int target = c + 3; if (target > NCH) target = NCH;
      if (tid == 0){
        while (__hip_atomic_load(flgC, __ATOMIC_ACQUIRE, __HIP_MEMORY_SCOPE_AGENT) < target)
          __builtin_amdgcn_s_sleep(8);
      }
      __syncthreads();
    }
  }
}

// ---------------------------------------------------------------- final MLP (fp32)
__global__ void mlp_kernel(const float* __restrict__ hlast,
    const float* __restrict__ w1, const float* __restrict__ b1,
    const float* __restrict__ w2, const float* __restrict__ b2,
    const float* __restrict__ w3, const float* __restrict__ b3,
    float* __restrict__ out){
  int b = blockIdx.x, t = threadIdx.x;
  __shared__ float sh[128];
  __shared__ float s1[64];
  __shared__ float s2[32];
  sh[t] = hlast[b*H_ + t];
  sh[t+64] = hlast[b*H_ + t + 64];
  __syncthreads();
  if (t < 64){
    float d = b1[t];
    for (int k = 0; k < 128; ++k) d += sh[k]*w1[t*128+k];
    s1[t] = d;
  }
  __syncthreads();
  if (t < 32){
    float d = b2[t];
    for (int k = 0; k < 64; ++k) d += s1[k]*w2[t*64+k];
    s2[t] = d;
  }
  __syncthreads();
  if (t < 10){
    float d = b3[t];
    for (int k = 0; k < 32; ++k) d += s2[k]*w3[t*32+k];
    out[b*OUT_ + t] = d;
  }
}

// ---------------------------------------------------------------- launch
extern "C" void kernel_launch(void* const* d_in, const int* in_sizes, int n_in,
                              void* d_out, int out_size, void* d_ws, size_t ws_size,
                              hipStream_t stream){
  const float* x   = (const float*)d_in[0];
  const float* wih = (const float*)d_in[1];
  const float* whh = (const float*)d_in[2];
  const float* bih = (const float*)d_in[3];
  const float* bhh = (const float*)d_in[4];
  const float* w1  = (const float*)d_in[5];
  const float* b1  = (const float*)d_in[6];
  const float* w2  = (const float*)d_in[7];
  const float* b2  = (const float*)d_in[8];
  const float* w3  = (const float*)d_in[9];
  const float* b3  = (const float*)d_in[10];
  float* out = (float*)d_out;

  char* ws = (char*)d_ws;
  uint16_t* A0   = (uint16_t*)(ws);                     // 33554432 B
  uint16_t* H1   = (uint16_t*)(ws + 33554432);          // 33554432 B
  uint16_t* H2   = (uint16_t*)(ws + 67108864);          // 33554432 B
  uint16_t* WIHS = (uint16_t*)(ws + 100663296);         // 393216 B
  uint16_t* WHHS = (uint16_t*)(ws + 101056512);         // 393216 B
  float*    BSCL = (float*)   (ws + 101449728);         // 6144 B
  float*    HL   = (float*)   (ws + 101455872);         // 32768 B
  int*      FLG  = (int*)     (ws + 101488640);         // 128 B

  prep_kernel<<<2048, 256, 0, stream>>>(x, wih, whh, bih, bhh, A0, WIHS, WHHS, BSCL, FLG);
  fused_kernel<<<12, 512, 0, stream>>>(A0, H1, H2, WIHS, WHHS, BSCL, HL, FLG);
  mlp_kernel<<<B_, 64, 0, stream>>>(HL, w1, b1, w2, b2, w3, b3, out);
}

// Round 16
// 1514.776 us; speedup vs baseline: 1.4886x; 1.4886x over previous
//
#include <hip/hip_runtime.h>
#include <stdint.h>

#define B_ 64
#define T_ 2048
#define H_ 128
#define G_ 512
#define NL 3
#define OUT_ 10
#define CHK 16
#define NCH (T_/CHK)

typedef __attribute__((ext_vector_type(8))) short bf16x8;
typedef __attribute__((ext_vector_type(4))) float f32x4;

#define MF(A,BW,C) __builtin_amdgcn_mfma_f32_16x16x32_bf16(A,BW,C,0,0,0)

__device__ __forceinline__ uint16_t f2bf(float f){
  union { float f; uint32_t u; } v; v.f = f;
  uint32_t u = v.u;
  uint32_t r = (u + 0x7FFFu + ((u >> 16) & 1u)) >> 16;
  return (uint16_t)r;
}
__device__ __forceinline__ float asf(uint32_t u){
  union { uint32_t u; float f; } v; v.u = u; return v.f;
}

// Barrier WITHOUT vmcnt(0) drain: LDS ordering only.
__device__ __forceinline__ void wg_barrier(){
  asm volatile("s_waitcnt lgkmcnt(0)" ::: "memory");
  __builtin_amdgcn_sched_barrier(0);
  __builtin_amdgcn_s_barrier();
  __builtin_amdgcn_sched_barrier(0);
}

// ---------------------------------------------------------------- prep
// Weights pre-scaled per gate (i,f,o: -log2e; g: +2*log2e) so gates become
// rcp(1+exp2(x)); bias likewise pre-scaled (folded into burst C-init).
__global__ void prep_kernel(const float* __restrict__ x,
                            const float* __restrict__ wih, const float* __restrict__ whh,
                            const float* __restrict__ bih, const float* __restrict__ bhh,
                            uint16_t* __restrict__ A0, uint16_t* __restrict__ WIHS,
                            uint16_t* __restrict__ WHHS, float* __restrict__ BSCL,
                            int* __restrict__ flags){
  int stride = gridDim.x * blockDim.x;
  int g0 = blockIdx.x * blockDim.x + threadIdx.x;
  for (int i = g0; i < B_*T_*H_; i += stride) A0[i] = f2bf(x[i]);
  for (int i = g0; i < NL*G_*H_; i += stride){
    int n = (i >> 7) & 511;
    float sc = ((n >> 7) == 2) ? 2.88539008f : -1.44269504f;
    WIHS[i] = f2bf(wih[i] * sc);
    WHHS[i] = f2bf(whh[i] * sc);
  }
  for (int i = g0; i < NL*G_; i += stride){
    float sc = (((i & 511) >> 7) == 2) ? 2.88539008f : -1.44269504f;
    BSCL[i] = (bih[i] + bhh[i]) * sc;
  }
  if (g0 < 32) flags[g0] = 0;
}

// ---------------------------------------------------------------- fused pipelined scan
// 48 WGs: layer = wg/16, q = wg%16 (4 batches). gx amortized — one 16-MFMA
// burst per 4-step window computes gx for 4 future steps (A-tile = 4
// batches x 4 timesteps, 100% dense; C-init = scaled bias). Output lane
// (hi,lo) reg r = gx(b=r, t=tg+hi). R16: pack via f2bf (plain C) — NOT
// inline-asm cvt_pk — so the compiler inserts the MFMA-result->VALU-read
// hazard waits (asm consumers of raw MFMA accumulators read mid-flight:
// the 5x NaN class). Each step broadcasts lane (t&3)*16+lo's packed pair
// via in-wave ds_bpermute, expands to f32 = rec-chain C-init. Rec chain:
// 16 h-MFMAs (R4-proven). Per SIMD: 40 MFMAs/step vs R12's 64.
// Layer handoff: R5/R9/R12-proven chunk flags (fresh addresses only).

#define LOADXW(tg) do { \
    if ((tg) < T_){ \
      const uint16_t* xb_ = Xin + xoB + (size_t)(tg)*H_; \
      ax[0] = *(const bf16x8*)(xb_); \
      ax[1] = *(const bf16x8*)(xb_ + 32); \
      ax[2] = *(const bf16x8*)(xb_ + 64); \
      ax[3] = *(const bf16x8*)(xb_ + 96); \
    } \
  } while(0)

// Burst for window tg: consumes ax = x[tg..tg+3], fills BP[0..7] =
// per-gate packed bf16 pairs: BP[2g] = pk(b0,b1), BP[2g+1] = pk(b2,b3).
#define BURSTW(BP, tg) do { \
    if ((tg) < T_){ \
      f32x4 c0 = binit0, c1 = binit1, c2 = binit2, c3 = binit3; \
      c0 = MF(ax[0], bwih[0][0], c0); c1 = MF(ax[0], bwih[1][0], c1); \
      c2 = MF(ax[0], bwih[2][0], c2); c3 = MF(ax[0], bwih[3][0], c3); \
      c0 = MF(ax[1], bwih[0][1], c0); c1 = MF(ax[1], bwih[1][1], c1); \
      c2 = MF(ax[1], bwih[2][1], c2); c3 = MF(ax[1], bwih[3][1], c3); \
      c0 = MF(ax[2], bwih[0][2], c0); c1 = MF(ax[2], bwih[1][2], c1); \
      c2 = MF(ax[2], bwih[2][2], c2); c3 = MF(ax[2], bwih[3][2], c3); \
      c0 = MF(ax[3], bwih[0][3], c0); c1 = MF(ax[3], bwih[1][3], c1); \
      c2 = MF(ax[3], bwih[2][3], c2); c3 = MF(ax[3], bwih[3][3], c3); \
      BP[0] = (uint32_t)f2bf(c0[0]) | ((uint32_t)f2bf(c0[1]) << 16); \
      BP[1] = (uint32_t)f2bf(c0[2]) | ((uint32_t)f2bf(c0[3]) << 16); \
      BP[2] = (uint32_t)f2bf(c1[0]) | ((uint32_t)f2bf(c1[1]) << 16); \
      BP[3] = (uint32_t)f2bf(c1[2]) | ((uint32_t)f2bf(c1[3]) << 16); \
      BP[4] = (uint32_t)f2bf(c2[0]) | ((uint32_t)f2bf(c2[1]) << 16); \
      BP[5] = (uint32_t)f2bf(c2[2]) | ((uint32_t)f2bf(c2[3]) << 16); \
      BP[6] = (uint32_t)f2bf(c3[0]) | ((uint32_t)f2bf(c3[1]) << 16); \
      BP[7] = (uint32_t)f2bf(c3[2]) | ((uint32_t)f2bf(c3[3]) << 16); \
    } \
  } while(0)

// One scan step. k = t&3 (compile-time). BP = current window's packed gx.
#define STEP(tcur, k, BP) do { \
    int bpa = ((k)*16 + lo) * 4; \
    uint32_t p00 = __builtin_amdgcn_ds_bpermute(bpa, (int)BP[0]); \
    uint32_t p01 = __builtin_amdgcn_ds_bpermute(bpa, (int)BP[1]); \
    uint32_t p10 = __builtin_amdgcn_ds_bpermute(bpa, (int)BP[2]); \
    uint32_t p11 = __builtin_amdgcn_ds_bpermute(bpa, (int)BP[3]); \
    uint32_t p20 = __builtin_amdgcn_ds_bpermute(bpa, (int)BP[4]); \
    uint32_t p21 = __builtin_amdgcn_ds_bpermute(bpa, (int)BP[5]); \
    uint32_t p30 = __builtin_amdgcn_ds_bpermute(bpa, (int)BP[6]); \
    uint32_t p31 = __builtin_amdgcn_ds_bpermute(bpa, (int)BP[7]); \
    f32x4 a0 = {asf(p00 << 16), asf(p00 & 0xffff0000u), asf(p01 << 16), asf(p01 & 0xffff0000u)}; \
    f32x4 a1 = {asf(p10 << 16), asf(p10 & 0xffff0000u), asf(p11 << 16), asf(p11 & 0xffff0000u)}; \
    f32x4 a2 = {asf(p20 << 16), asf(p20 & 0xffff0000u), asf(p21 << 16), asf(p21 & 0xffff0000u)}; \
    f32x4 a3 = {asf(p30 << 16), asf(p30 & 0xffff0000u), asf(p31 << 16), asf(p31 & 0xffff0000u)}; \
    bf16x8 af0 = *(const bf16x8*)((const char*)RBp + afo0); \
    bf16x8 af1 = *(const bf16x8*)((const char*)RBp + afo1); \
    bf16x8 af2 = *(const bf16x8*)((const char*)RBp + afo2); \
    bf16x8 af3 = *(const bf16x8*)((const char*)RBp + afo3); \
    a0 = MF(af0, bwhh[0][0], a0); a1 = MF(af0, bwhh[1][0], a1); \
    a2 = MF(af0, bwhh[2][0], a2); a3 = MF(af0, bwhh[3][0], a3); \
    a0 = MF(af1, bwhh[0][1], a0); a1 = MF(af1, bwhh[1][1], a1); \
    a2 = MF(af1, bwhh[2][1], a2); a3 = MF(af1, bwhh[3][1], a3); \
    a0 = MF(af2, bwhh[0][2], a0); a1 = MF(af2, bwhh[1][2], a1); \
    a2 = MF(af2, bwhh[2][2], a2); a3 = MF(af2, bwhh[3][2], a3); \
    a0 = MF(af3, bwhh[0][3], a0); a1 = MF(af3, bwhh[1][3], a1); \
    a2 = MF(af3, bwhh[2][3], a2); a3 = MF(af3, bwhh[3][3], a3); \
    float p0 = hiB1 ? a0[1] : a0[0]; float q0 = hiB1 ? a0[3] : a0[2]; \
    float p1 = hiB1 ? a1[1] : a1[0]; float q1 = hiB1 ? a1[3] : a1[2]; \
    float p2 = hiB1 ? a2[1] : a2[0]; float q2 = hiB1 ? a2[3] : a2[2]; \
    float p3 = hiB1 ? a3[1] : a3[0]; float q3 = hiB1 ? a3[3] : a3[2]; \
    float x0 = hiB2 ? q0 : p0; \
    float x1 = hiB2 ? q1 : p1; \
    float x2 = hiB2 ? q2 : p2; \
    float x3 = hiB2 ? q3 : p3; \
    float iv = __builtin_amdgcn_rcpf(1.0f + __builtin_amdgcn_exp2f(x0)); \
    float fv = __builtin_amdgcn_rcpf(1.0f + __builtin_amdgcn_exp2f(x1)); \
    float gt = __builtin_amdgcn_rcpf(1.0f + __builtin_amdgcn_exp2f(x2)); \
    float ov = __builtin_amdgcn_rcpf(1.0f + __builtin_amdgcn_exp2f(x3)); \
    float gv = __builtin_fmaf(-2.0f, gt, 1.0f); \
    cst = fv * cst + iv * gv; \
    float tt = __builtin_amdgcn_rcpf(1.0f + __builtin_amdgcn_exp2f(2.88539008f * cst)); \
    float th = __builtin_fmaf(-2.0f, tt, 1.0f); \
    float hval = ov * th; \
    uint32_t hp; \
    asm("v_cvt_pk_bf16_f32 %0, %1, %2" : "=v"(hp) : "v"(hval), "v"(hval)); \
    *(uint16_t*)((char*)WBp + hw_off) = (uint16_t)hp; \
    if (layer < 2){ \
      Hout[houtBase + (size_t)(tcur)*H_] = (uint16_t)hp; \
    } else if ((tcur) == T_-1){ \
      hlast[(b0+hi)*H_ + j] = hval; \
    } \
    wg_barrier(); \
    { uint16_t* tmp_ = RBp; RBp = WBp; WBp = tmp_; } \
  } while(0)

__global__ __launch_bounds__(512, 2) void fused_kernel(
    const uint16_t* __restrict__ A0, uint16_t* __restrict__ H1,
    uint16_t* __restrict__ H2, const uint16_t* __restrict__ WIHS,
    const uint16_t* __restrict__ WHHS, const float* __restrict__ BSCL,
    float* __restrict__ hlast, int* __restrict__ flags){
  __shared__ uint16_t hb0[4*128];
  __shared__ uint16_t hb1[4*128];
  int tid = threadIdx.x;
  int wg = blockIdx.x;
  int layer = wg >> 4, q = wg & 15;
  int b0 = q * 4;
  int w = tid >> 6, l = tid & 63, lo = l & 15, hi = l >> 4;
  int j = w*16 + lo;
  bool hiB1 = (hi & 1), hiB2 = (hi & 2);

  const uint16_t* Xin = (layer == 0) ? A0 : ((layer == 1) ? H1 : H2);
  uint16_t* Hout = (layer == 0) ? H1 : H2;   // unused for layer 2
  int* flgP = flags + layer*16 + q;          // producer flag (layer<2)
  int* flgC = flags + (layer-1)*16 + q;      // consumer flag (layer>0)

  const uint16_t* wihL = WIHS + layer*G_*H_;
  const uint16_t* whhL = WHHS + layer*G_*H_;

  bf16x8 bwih[4][4], bwhh[4][4];
#pragma unroll
  for (int g = 0; g < 4; ++g)
#pragma unroll
    for (int kc = 0; kc < 4; ++kc){
      bwih[g][kc] = *(const bf16x8*)(wihL + (g*128 + j)*H_ + kc*32 + hi*8);
      bwhh[g][kc] = *(const bf16x8*)(whhL + (g*128 + j)*H_ + kc*32 + hi*8);
    }

  float bs0 = BSCL[layer*G_ +       j];
  float bs1 = BSCL[layer*G_ + 128 + j];
  float bs2 = BSCL[layer*G_ + 256 + j];
  float bs3 = BSCL[layer*G_ + 384 + j];
  f32x4 binit0 = {bs0,bs0,bs0,bs0};
  f32x4 binit1 = {bs1,bs1,bs1,bs1};
  f32x4 binit2 = {bs2,bs2,bs2,bs2};
  f32x4 binit3 = {bs3,bs3,bs3,bs3};

  // A-frag h-tile offsets (R4-verified swizzle, 0 bank conflicts)
  int rb = lo & 3;
  int swr = ((rb & 1) << 6) | ((rb >> 1) << 5);
  int afo0 = rb*256 + ((  0 + hi*16) ^ swr);
  int afo1 = rb*256 + (( 64 + hi*16) ^ swr);
  int afo2 = rb*256 + ((128 + hi*16) ^ swr);
  int afo3 = rb*256 + ((192 + hi*16) ^ swr);
  int hw_off = hi*256 + ((j*2) ^ (((hi & 1) << 6) | ((hi >> 1) << 5)));
  size_t houtBase = (size_t)(b0 + hi) * T_ * H_ + j;

  // x A-tile base: row lo = (batch lo&3, time-offset lo>>2), k = hi*8
  size_t xoB = (size_t)(b0 + (lo & 3)) * T_ * H_ + (size_t)(lo >> 2) * H_ + hi*8;

  float cst = 0.0f;
  hb0[tid] = 0;
  hb1[tid] = 0;

  if (layer > 0 && tid == 0){
    while (__hip_atomic_load(flgC, __ATOMIC_ACQUIRE, __HIP_MEMORY_SCOPE_AGENT) < 2)
      __builtin_amdgcn_s_sleep(8);
  }
  __syncthreads();

  bf16x8 ax[4];
  uint32_t bA[8], bB[8];
  LOADXW(0);          // ax = x[0..3]
  BURSTW(bA, 0);      // gx for steps 0..3
  LOADXW(4);          // ax = x[4..7] for the first in-loop burst

  uint16_t* RBp = hb0;
  uint16_t* WBp = hb1;

  for (int c = 0; c < NCH; ++c){
    int tb = c * CHK;
    // window 0: steps tb..tb+3 use bA
    BURSTW(bB, tb+4);  LOADXW(tb+8);
    STEP(tb+0, 0, bA); STEP(tb+1, 1, bA); STEP(tb+2, 2, bA); STEP(tb+3, 3, bA);
    // window 1: steps tb+4..tb+7 use bB
    BURSTW(bA, tb+8);  LOADXW(tb+12);
    STEP(tb+4, 0, bB); STEP(tb+5, 1, bB); STEP(tb+6, 2, bB); STEP(tb+7, 3, bB);
    // window 2
    BURSTW(bB, tb+12); LOADXW(tb+16);
    STEP(tb+8, 0, bA); STEP(tb+9, 1, bA); STEP(tb+10, 2, bA); STEP(tb+11, 3, bA);
    // window 3
    BURSTW(bA, tb+16); LOADXW(tb+20);
    STEP(tb+12, 0, bB); STEP(tb+13, 1, bB); STEP(tb+14, 2, bB); STEP(tb+15, 3, bB);

    if (layer < 2){
      asm volatile("s_waitcnt vmcnt(0)" ::: "memory");
      __syncthreads();
      if (tid == 0)
        __hip_atomic_store(flgP, c + 1, __ATOMIC_RELEASE, __HIP_MEMORY_SCOPE_AGENT);
    }
    if (layer > 0 && c + 1 < NCH){
      int target = c + 3; if (target > NCH) target = NCH;
      if (tid == 0){
        while (__hip_atomic_load(flgC, __ATOMIC_ACQUIRE, __HIP_MEMORY_SCOPE_AGENT) < target)
          __builtin_amdgcn_s_sleep(8);
      }
      __syncthreads();
    }
  }
}

// ---------------------------------------------------------------- final MLP (fp32)
__global__ void mlp_kernel(const float* __restrict__ hlast,
    const float* __restrict__ w1, const float* __restrict__ b1,
    const float* __restrict__ w2, const float* __restrict__ b2,
    const float* __restrict__ w3, const float* __restrict__ b3,
    float* __restrict__ out){
  int b = blockIdx.x, t = threadIdx.x;
  __shared__ float sh[128];
  __shared__ float s1[64];
  __shared__ float s2[32];
  sh[t] = hlast[b*H_ + t];
  sh[t+64] = hlast[b*H_ + t + 64];
  __syncthreads();
  if (t < 64){
    float d = b1[t];
    for (int k = 0; k < 128; ++k) d += sh[k]*w1[t*128+k];
    s1[t] = d;
  }
  __syncthreads();
  if (t < 32){
    float d = b2[t];
    for (int k = 0; k < 64; ++k) d += s1[k]*w2[t*64+k];
    s2[t] = d;
  }
  __syncthreads();
  if (t < 10){
    float d = b3[t];
    for (int k = 0; k < 32; ++k) d += s2[k]*w3[t*32+k];
    out[b*OUT_ + t] = d;
  }
}

// ---------------------------------------------------------------- launch
extern "C" void kernel_launch(void* const* d_in, const int* in_sizes, int n_in,
                              void* d_out, int out_size, void* d_ws, size_t ws_size,
                              hipStream_t stream){
  const float* x   = (const float*)d_in[0];
  const float* wih = (const float*)d_in[1];
  const float* whh = (const float*)d_in[2];
  const float* bih = (const float*)d_in[3];
  const float* bhh = (const float*)d_in[4];
  const float* w1  = (const float*)d_in[5];
  const float* b1  = (const float*)d_in[6];
  const float* w2  = (const float*)d_in[7];
  const float* b2  = (const float*)d_in[8];
  const float* w3  = (const float*)d_in[9];
  const float* b3  = (const float*)d_in[10];
  float* out = (float*)d_out;

  char* ws = (char*)d_ws;
  uint16_t* A0   = (uint16_t*)(ws);                     // 33554432 B
  uint16_t* H1   = (uint16_t*)(ws + 33554432);          // 33554432 B
  uint16_t* H2   = (uint16_t*)(ws + 67108864);          // 33554432 B
  uint16_t* WIHS = (uint16_t*)(ws + 100663296);         // 393216 B
  uint16_t* WHHS = (uint16_t*)(ws + 101056512);         // 393216 B
  float*    BSCL = (float*)   (ws + 101449728);         // 6144 B
  float*    HL   = (float*)   (ws + 101455872);         // 32768 B
  int*      FLG  = (int*)     (ws + 101488640);         // 128 B

  prep_kernel<<<2048, 256, 0, stream>>>(x, wih, whh, bih, bhh, A0, WIHS, WHHS, BSCL, FLG);
  fused_kernel<<<48, 512, 0, stream>>>(A0, H1, H2, WIHS, WHHS, BSCL, HL, FLG);
  mlp_kernel<<<B_, 64, 0, stream>>>(HL, w1, b1, w2, b2, w3, b3, out);
}

// Round 17
// 1430.728 us; speedup vs baseline: 1.5760x; 1.0587x over previous
//
#include <hip/hip_runtime.h>
#include <stdint.h>

#define B_ 64
#define T_ 2048
#define H_ 128
#define G_ 512
#define NL 3
#define OUT_ 10
#define CHK 16
#define NCH (T_/CHK)

typedef __attribute__((ext_vector_type(8))) short bf16x8;
typedef __attribute__((ext_vector_type(4))) float f32x4;

#define MF(A,BW,C) __builtin_amdgcn_mfma_f32_16x16x32_bf16(A,BW,C,0,0,0)

__device__ __forceinline__ uint16_t f2bf(float f){
  union { float f; uint32_t u; } v; v.f = f;
  uint32_t u = v.u;
  uint32_t r = (u + 0x7FFFu + ((u >> 16) & 1u)) >> 16;
  return (uint16_t)r;
}
__device__ __forceinline__ float asf(uint32_t u){
  union { uint32_t u; float f; } v; v.u = u; return v.f;
}

// Barrier WITHOUT vmcnt(0) drain: LDS ordering only.
__device__ __forceinline__ void wg_barrier(){
  asm volatile("s_waitcnt lgkmcnt(0)" ::: "memory");
  __builtin_amdgcn_sched_barrier(0);
  __builtin_amdgcn_s_barrier();
  __builtin_amdgcn_sched_barrier(0);
}

// ---------------------------------------------------------------- prep
// Weights pre-scaled per gate (i,f,o: -log2e; g: +2*log2e) so gates become
// rcp(1+exp2(x)); bias likewise pre-scaled (folded into burst C-init).
__global__ void prep_kernel(const float* __restrict__ x,
                            const float* __restrict__ wih, const float* __restrict__ whh,
                            const float* __restrict__ bih, const float* __restrict__ bhh,
                            uint16_t* __restrict__ A0, uint16_t* __restrict__ WIHS,
                            uint16_t* __restrict__ WHHS, float* __restrict__ BSCL,
                            int* __restrict__ flags){
  int stride = gridDim.x * blockDim.x;
  int g0 = blockIdx.x * blockDim.x + threadIdx.x;
  for (int i = g0; i < B_*T_*H_; i += stride) A0[i] = f2bf(x[i]);
  for (int i = g0; i < NL*G_*H_; i += stride){
    int n = (i >> 7) & 511;
    float sc = ((n >> 7) == 2) ? 2.88539008f : -1.44269504f;
    WIHS[i] = f2bf(wih[i] * sc);
    WHHS[i] = f2bf(whh[i] * sc);
  }
  for (int i = g0; i < NL*G_; i += stride){
    float sc = (((i & 511) >> 7) == 2) ? 2.88539008f : -1.44269504f;
    BSCL[i] = (bih[i] + bhh[i]) * sc;
  }
  if (g0 < 32) flags[g0] = 0;
}

// ---------------------------------------------------------------- fused pipelined scan
// 48 WGs: layer = wg/16, q = wg%16 (4 batches). gx amortized — one 16-MFMA
// burst per 4-step window (A = 4 batches x 4 timesteps, dense; C-init =
// scaled bias), packed via f2bf (compiler-visible: inserts MFMA->VALU
// hazard waits; inline-asm cvt_pk on raw accumulators = the 5x NaN class).
// R17: C-init PIPELINED — step t computes step t+1's C-init (8 ds_bpermute
// + unpack into ping-ponged ci sets) after issuing its rec MFMAs, so each
// step's critical path is barrier -> ds_read -> MFMA with no bpermute in
// front. Rec chain: 16 h-MFMAs (R4-proven). 40 MFMAs/SIMD/step.
// Layer handoff: R5/R9/R12-proven chunk flags (fresh addresses only).

#define LOADXW(tg) do { \
    if ((tg) < T_){ \
      const uint16_t* xb_ = Xin + xoB + (size_t)(tg)*H_; \
      ax[0] = *(const bf16x8*)(xb_); \
      ax[1] = *(const bf16x8*)(xb_ + 32); \
      ax[2] = *(const bf16x8*)(xb_ + 64); \
      ax[3] = *(const bf16x8*)(xb_ + 96); \
    } \
  } while(0)

// Burst for window tg: consumes ax = x[tg..tg+3], fills BP[0..7] =
// per-gate packed bf16 pairs: BP[2g] = pk(b0,b1), BP[2g+1] = pk(b2,b3).
#define BURSTW(BP, tg) do { \
    if ((tg) < T_){ \
      f32x4 c0 = binit0, c1 = binit1, c2 = binit2, c3 = binit3; \
      c0 = MF(ax[0], bwih[0][0], c0); c1 = MF(ax[0], bwih[1][0], c1); \
      c2 = MF(ax[0], bwih[2][0], c2); c3 = MF(ax[0], bwih[3][0], c3); \
      c0 = MF(ax[1], bwih[0][1], c0); c1 = MF(ax[1], bwih[1][1], c1); \
      c2 = MF(ax[1], bwih[2][1], c2); c3 = MF(ax[1], bwih[3][1], c3); \
      c0 = MF(ax[2], bwih[0][2], c0); c1 = MF(ax[2], bwih[1][2], c1); \
      c2 = MF(ax[2], bwih[2][2], c2); c3 = MF(ax[2], bwih[3][2], c3); \
      c0 = MF(ax[3], bwih[0][3], c0); c1 = MF(ax[3], bwih[1][3], c1); \
      c2 = MF(ax[3], bwih[2][3], c2); c3 = MF(ax[3], bwih[3][3], c3); \
      BP[0] = (uint32_t)f2bf(c0[0]) | ((uint32_t)f2bf(c0[1]) << 16); \
      BP[1] = (uint32_t)f2bf(c0[2]) | ((uint32_t)f2bf(c0[3]) << 16); \
      BP[2] = (uint32_t)f2bf(c1[0]) | ((uint32_t)f2bf(c1[1]) << 16); \
      BP[3] = (uint32_t)f2bf(c1[2]) | ((uint32_t)f2bf(c1[3]) << 16); \
      BP[4] = (uint32_t)f2bf(c2[0]) | ((uint32_t)f2bf(c2[1]) << 16); \
      BP[5] = (uint32_t)f2bf(c2[2]) | ((uint32_t)f2bf(c2[3]) << 16); \
      BP[6] = (uint32_t)f2bf(c3[0]) | ((uint32_t)f2bf(c3[1]) << 16); \
      BP[7] = (uint32_t)f2bf(c3[2]) | ((uint32_t)f2bf(c3[3]) << 16); \
    } \
  } while(0)

// Build C-init set CI[0..3] for step with in-window index kn from packed BPn.
#define CINIT(CI, kn, BPn) do { \
    int bpa_ = ((kn)*16 + lo) * 4; \
    uint32_t q0_ = __builtin_amdgcn_ds_bpermute(bpa_, (int)BPn[0]); \
    uint32_t q1_ = __builtin_amdgcn_ds_bpermute(bpa_, (int)BPn[1]); \
    uint32_t q2_ = __builtin_amdgcn_ds_bpermute(bpa_, (int)BPn[2]); \
    uint32_t q3_ = __builtin_amdgcn_ds_bpermute(bpa_, (int)BPn[3]); \
    uint32_t q4_ = __builtin_amdgcn_ds_bpermute(bpa_, (int)BPn[4]); \
    uint32_t q5_ = __builtin_amdgcn_ds_bpermute(bpa_, (int)BPn[5]); \
    uint32_t q6_ = __builtin_amdgcn_ds_bpermute(bpa_, (int)BPn[6]); \
    uint32_t q7_ = __builtin_amdgcn_ds_bpermute(bpa_, (int)BPn[7]); \
    CI[0][0] = asf(q0_ << 16); CI[0][1] = asf(q0_ & 0xffff0000u); \
    CI[0][2] = asf(q1_ << 16); CI[0][3] = asf(q1_ & 0xffff0000u); \
    CI[1][0] = asf(q2_ << 16); CI[1][1] = asf(q2_ & 0xffff0000u); \
    CI[1][2] = asf(q3_ << 16); CI[1][3] = asf(q3_ & 0xffff0000u); \
    CI[2][0] = asf(q4_ << 16); CI[2][1] = asf(q4_ & 0xffff0000u); \
    CI[2][2] = asf(q5_ << 16); CI[2][3] = asf(q5_ & 0xffff0000u); \
    CI[3][0] = asf(q6_ << 16); CI[3][1] = asf(q6_ & 0xffff0000u); \
    CI[3][2] = asf(q7_ << 16); CI[3][3] = asf(q7_ & 0xffff0000u); \
  } while(0)

// One scan step: C-init CIc was precomputed last step; after issuing the
// rec MFMAs, build CIn (next step's C-init, window-index kn, packs BPn).
#define STEPP(tcur, CIc, CIn, kn, BPn) do { \
    bf16x8 af0 = *(const bf16x8*)((const char*)RBp + afo0); \
    bf16x8 af1 = *(const bf16x8*)((const char*)RBp + afo1); \
    bf16x8 af2 = *(const bf16x8*)((const char*)RBp + afo2); \
    bf16x8 af3 = *(const bf16x8*)((const char*)RBp + afo3); \
    f32x4 a0 = CIc[0], a1 = CIc[1], a2 = CIc[2], a3 = CIc[3]; \
    a0 = MF(af0, bwhh[0][0], a0); a1 = MF(af0, bwhh[1][0], a1); \
    a2 = MF(af0, bwhh[2][0], a2); a3 = MF(af0, bwhh[3][0], a3); \
    a0 = MF(af1, bwhh[0][1], a0); a1 = MF(af1, bwhh[1][1], a1); \
    a2 = MF(af1, bwhh[2][1], a2); a3 = MF(af1, bwhh[3][1], a3); \
    a0 = MF(af2, bwhh[0][2], a0); a1 = MF(af2, bwhh[1][2], a1); \
    a2 = MF(af2, bwhh[2][2], a2); a3 = MF(af2, bwhh[3][2], a3); \
    a0 = MF(af3, bwhh[0][3], a0); a1 = MF(af3, bwhh[1][3], a1); \
    a2 = MF(af3, bwhh[2][3], a2); a3 = MF(af3, bwhh[3][3], a3); \
    CINIT(CIn, kn, BPn); \
    float p0 = hiB1 ? a0[1] : a0[0]; float q0 = hiB1 ? a0[3] : a0[2]; \
    float p1 = hiB1 ? a1[1] : a1[0]; float q1 = hiB1 ? a1[3] : a1[2]; \
    float p2 = hiB1 ? a2[1] : a2[0]; float q2 = hiB1 ? a2[3] : a2[2]; \
    float p3 = hiB1 ? a3[1] : a3[0]; float q3 = hiB1 ? a3[3] : a3[2]; \
    float x0 = hiB2 ? q0 : p0; \
    float x1 = hiB2 ? q1 : p1; \
    float x2 = hiB2 ? q2 : p2; \
    float x3 = hiB2 ? q3 : p3; \
    float iv = __builtin_amdgcn_rcpf(1.0f + __builtin_amdgcn_exp2f(x0)); \
    float fv = __builtin_amdgcn_rcpf(1.0f + __builtin_amdgcn_exp2f(x1)); \
    float gt = __builtin_amdgcn_rcpf(1.0f + __builtin_amdgcn_exp2f(x2)); \
    float ov = __builtin_amdgcn_rcpf(1.0f + __builtin_amdgcn_exp2f(x3)); \
    float gv = __builtin_fmaf(-2.0f, gt, 1.0f); \
    cst = fv * cst + iv * gv; \
    float tt = __builtin_amdgcn_rcpf(1.0f + __builtin_amdgcn_exp2f(2.88539008f * cst)); \
    float th = __builtin_fmaf(-2.0f, tt, 1.0f); \
    float hval = ov * th; \
    uint32_t hp; \
    asm("v_cvt_pk_bf16_f32 %0, %1, %2" : "=v"(hp) : "v"(hval), "v"(hval)); \
    *(uint16_t*)((char*)WBp + hw_off) = (uint16_t)hp; \
    if (layer < 2){ \
      Hout[houtBase + (size_t)(tcur)*H_] = (uint16_t)hp; \
    } else if ((tcur) == T_-1){ \
      hlast[(b0+hi)*H_ + j] = hval; \
    } \
    wg_barrier(); \
    { uint16_t* tmp_ = RBp; RBp = WBp; WBp = tmp_; } \
  } while(0)

__global__ __launch_bounds__(512, 2) void fused_kernel(
    const uint16_t* __restrict__ A0, uint16_t* __restrict__ H1,
    uint16_t* __restrict__ H2, const uint16_t* __restrict__ WIHS,
    const uint16_t* __restrict__ WHHS, const float* __restrict__ BSCL,
    float* __restrict__ hlast, int* __restrict__ flags){
  __shared__ uint16_t hb0[4*128];
  __shared__ uint16_t hb1[4*128];
  int tid = threadIdx.x;
  int wg = blockIdx.x;
  int layer = wg >> 4, q = wg & 15;
  int b0 = q * 4;
  int w = tid >> 6, l = tid & 63, lo = l & 15, hi = l >> 4;
  int j = w*16 + lo;
  bool hiB1 = (hi & 1), hiB2 = (hi & 2);

  const uint16_t* Xin = (layer == 0) ? A0 : ((layer == 1) ? H1 : H2);
  uint16_t* Hout = (layer == 0) ? H1 : H2;   // unused for layer 2
  int* flgP = flags + layer*16 + q;          // producer flag (layer<2)
  int* flgC = flags + (layer-1)*16 + q;      // consumer flag (layer>0)

  const uint16_t* wihL = WIHS + layer*G_*H_;
  const uint16_t* whhL = WHHS + layer*G_*H_;

  bf16x8 bwih[4][4], bwhh[4][4];
#pragma unroll
  for (int g = 0; g < 4; ++g)
#pragma unroll
    for (int kc = 0; kc < 4; ++kc){
      bwih[g][kc] = *(const bf16x8*)(wihL + (g*128 + j)*H_ + kc*32 + hi*8);
      bwhh[g][kc] = *(const bf16x8*)(whhL + (g*128 + j)*H_ + kc*32 + hi*8);
    }

  float bs0 = BSCL[layer*G_ +       j];
  float bs1 = BSCL[layer*G_ + 128 + j];
  float bs2 = BSCL[layer*G_ + 256 + j];
  float bs3 = BSCL[layer*G_ + 384 + j];
  f32x4 binit0 = {bs0,bs0,bs0,bs0};
  f32x4 binit1 = {bs1,bs1,bs1,bs1};
  f32x4 binit2 = {bs2,bs2,bs2,bs2};
  f32x4 binit3 = {bs3,bs3,bs3,bs3};

  // A-frag h-tile offsets (R4-verified swizzle, 0 bank conflicts)
  int rb = lo & 3;
  int swr = ((rb & 1) << 6) | ((rb >> 1) << 5);
  int afo0 = rb*256 + ((  0 + hi*16) ^ swr);
  int afo1 = rb*256 + (( 64 + hi*16) ^ swr);
  int afo2 = rb*256 + ((128 + hi*16) ^ swr);
  int afo3 = rb*256 + ((192 + hi*16) ^ swr);
  int hw_off = hi*256 + ((j*2) ^ (((hi & 1) << 6) | ((hi >> 1) << 5)));
  size_t houtBase = (size_t)(b0 + hi) * T_ * H_ + j;

  // x A-tile base: row lo = (batch lo&3, time-offset lo>>2), k = hi*8
  size_t xoB = (size_t)(b0 + (lo & 3)) * T_ * H_ + (size_t)(lo >> 2) * H_ + hi*8;

  float cst = 0.0f;
  hb0[tid] = 0;
  hb1[tid] = 0;

  if (layer > 0 && tid == 0){
    while (__hip_atomic_load(flgC, __ATOMIC_ACQUIRE, __HIP_MEMORY_SCOPE_AGENT) < 2)
      __builtin_amdgcn_s_sleep(8);
  }
  __syncthreads();

  bf16x8 ax[4];
  uint32_t bA[8], bB[8];
  f32x4 ciA[4], ciB[4];
  LOADXW(0);           // ax = x[0..3]
  BURSTW(bA, 0);       // gx for steps 0..3
  LOADXW(4);           // ax = x[4..7] for the first in-loop burst
  CINIT(ciA, 0, bA);   // C-init for step 0

  uint16_t* RBp = hb0;
  uint16_t* WBp = hb1;

  for (int c = 0; c < NCH; ++c){
    int tb = c * CHK;
    // window 0 (steps tb..tb+3 use bA)
    BURSTW(bB, tb+4);  LOADXW(tb+8);
    STEPP(tb+0,  ciA, ciB, 1, bA);
    STEPP(tb+1,  ciB, ciA, 2, bA);
    STEPP(tb+2,  ciA, ciB, 3, bA);
    STEPP(tb+3,  ciB, ciA, 0, bB);
    // window 1 (bB)
    BURSTW(bA, tb+8);  LOADXW(tb+12);
    STEPP(tb+4,  ciA, ciB, 1, bB);
    STEPP(tb+5,  ciB, ciA, 2, bB);
    STEPP(tb+6,  ciA, ciB, 3, bB);
    STEPP(tb+7,  ciB, ciA, 0, bA);
    // window 2 (bA)
    BURSTW(bB, tb+12); LOADXW(tb+16);
    STEPP(tb+8,  ciA, ciB, 1, bA);
    STEPP(tb+9,  ciB, ciA, 2, bA);
    STEPP(tb+10, ciA, ciB, 3, bA);
    STEPP(tb+11, ciB, ciA, 0, bB);
    // window 3 (bB)
    BURSTW(bA, tb+16); LOADXW(tb+20);
    STEPP(tb+12, ciA, ciB, 1, bB);
    STEPP(tb+13, ciB, ciA, 2, bB);
    STEPP(tb+14, ciA, ciB, 3, bB);
    STEPP(tb+15, ciB, ciA, 0, bA);

    if (layer < 2){
      asm volatile("s_waitcnt vmcnt(0)" ::: "memory");
      __syncthreads();
      if (tid == 0)
        __hip_atomic_store(flgP, c + 1, __ATOMIC_RELEASE, __HIP_MEMORY_SCOPE_AGENT);
    }
    if (layer > 0 && c + 1 < NCH){
      int target = c + 3; if (target > NCH) target = NCH;
      if (tid == 0){
        while (__hip_atomic_load(flgC, __ATOMIC_ACQUIRE, __HIP_MEMORY_SCOPE_AGENT) < target)
          __builtin_amdgcn_s_sleep(8);
      }
      __syncthreads();
    }
  }
}

// ---------------------------------------------------------------- final MLP (fp32)
__global__ void mlp_kernel(const float* __restrict__ hlast,
    const float* __restrict__ w1, const float* __restrict__ b1,
    const float* __restrict__ w2, const float* __restrict__ b2,
    const float* __restrict__ w3, const float* __restrict__ b3,
    float* __restrict__ out){
  int b = blockIdx.x, t = threadIdx.x;
  __shared__ float sh[128];
  __shared__ float s1[64];
  __shared__ float s2[32];
  sh[t] = hlast[b*H_ + t];
  sh[t+64] = hlast[b*H_ + t + 64];
  __syncthreads();
  if (t < 64){
    float d = b1[t];
    for (int k = 0; k < 128; ++k) d += sh[k]*w1[t*128+k];
    s1[t] = d;
  }
  __syncthreads();
  if (t < 32){
    float d = b2[t];
    for (int k = 0; k < 64; ++k) d += s1[k]*w2[t*64+k];
    s2[t] = d;
  }
  __syncthreads();
  if (t < 10){
    float d = b3[t];
    for (int k = 0; k < 32; ++k) d += s2[k]*w3[t*32+k];
    out[b*OUT_ + t] = d;
  }
}

// ---------------------------------------------------------------- launch
extern "C" void kernel_launch(void* const* d_in, const int* in_sizes, int n_in,
                              void* d_out, int out_size, void* d_ws, size_t ws_size,
                              hipStream_t stream){
  const float* x   = (const float*)d_in[0];
  const float* wih = (const float*)d_in[1];
  const float* whh = (const float*)d_in[2];
  const float* bih = (const float*)d_in[3];
  const float* bhh = (const float*)d_in[4];
  const float* w1  = (const float*)d_in[5];
  const float* b1  = (const float*)d_in[6];
  const float* w2  = (const float*)d_in[7];
  const float* b2  = (const float*)d_in[8];
  const float* w3  = (const float*)d_in[9];
  const float* b3  = (const float*)d_in[10];
  float* out = (float*)d_out;

  char* ws = (char*)d_ws;
  uint16_t* A0   = (uint16_t*)(ws);                     // 33554432 B
  uint16_t* H1   = (uint16_t*)(ws + 33554432);          // 33554432 B
  uint16_t* H2   = (uint16_t*)(ws + 67108864);          // 33554432 B
  uint16_t* WIHS = (uint16_t*)(ws + 100663296);         // 393216 B
  uint16_t* WHHS = (uint16_t*)(ws + 101056512);         // 393216 B
  float*    BSCL = (float*)   (ws + 101449728);         // 6144 B
  float*    HL   = (float*)   (ws + 101455872);         // 32768 B
  int*      FLG  = (int*)     (ws + 101488640);         // 128 B

  prep_kernel<<<2048, 256, 0, stream>>>(x, wih, whh, bih, bhh, A0, WIHS, WHHS, BSCL, FLG);
  fused_kernel<<<48, 512, 0, stream>>>(A0, H1, H2, WIHS, WHHS, BSCL, HL, FLG);
  mlp_kernel<<<B_, 64, 0, stream>>>(HL, w1, b1, w2, b2, w3, b3, out);
}